// Round 10
// baseline (70.012 us; speedup 1.0000x reference)
//
#include <hip/hip_runtime.h>
#include <hip/hip_bf16.h>
#include <math.h>

// out[b,i,j,o] = lrelu( sum_k pe[d_k]@W_k[:,o] + b[o] )
// (1) Y[k][r][o] = pe[r,:]@W_k[:,o] (+bias at k==0), fp32 math, bf16 store.
//     Table = 2.1 MB (L2-resident; R7 proved >4MB tables fall to ~3TB/s L3 path).
// (2) gather2: 2 j's per wave (measured optimum over 1/2/4/16), 4x 8B row
//     loads + 2x 1KB coalesced PLAIN stores per wave.
// R10 single-variable A/B: nontemporal -> plain stores (NT was never isolated;
// model says NT drains at ~3TB/s vs 6.5TB/s through-L2).

typedef float f32x4 __attribute__((ext_vector_type(4)));

__device__ __forceinline__ float lrelu(float x) { return fmaxf(x, 0.01f * x); }
__device__ __forceinline__ float bflo(unsigned int v) {
    union { unsigned int i; float f; } c; c.i = v << 16; return c.f;
}
__device__ __forceinline__ float bfhi(unsigned int v) {
    union { unsigned int i; float f; } c; c.i = v & 0xffff0000u; return c.f;
}

// ---------------- Kernel 1: Y precompute (exact R4 version) -------------------
__global__ __launch_bounds__(256) void precompute_Y(
        const float* __restrict__ pe, const float* __restrict__ W,
        const float* __restrict__ bias, __hip_bfloat16* __restrict__ Y, int NPE) {
    const int H = 256;
    const int ntile = (NPE + 7) >> 3;
    const int k  = blockIdx.x / ntile;
    const int r0 = (blockIdx.x % ntile) << 3;
    const int o  = threadIdx.x;
    const float* __restrict__ Wk = W + (size_t)k * H * H;

    int rows[8];
#pragma unroll
    for (int r = 0; r < 8; ++r) rows[r] = min(r0 + r, NPE - 1);
    float acc[8];
#pragma unroll
    for (int r = 0; r < 8; ++r) acc[r] = 0.f;

#pragma unroll 2
    for (int h = 0; h < 256; h += 4) {
        const float w0 = Wk[(h + 0) * H + o];
        const float w1 = Wk[(h + 1) * H + o];
        const float w2 = Wk[(h + 2) * H + o];
        const float w3 = Wk[(h + 3) * H + o];
#pragma unroll
        for (int r = 0; r < 8; ++r) {
            const f32x4 p = *reinterpret_cast<const f32x4*>(&pe[rows[r] * H + h]);
            acc[r] += p.x * w0 + p.y * w1 + p.z * w2 + p.w * w3;
        }
    }
    const float bv = (k == 0) ? bias[o] : 0.f;
#pragma unroll
    for (int r = 0; r < 8; ++r) {
        const int rr = r0 + r;
        if (rr < NPE)
            Y[((size_t)k * NPE + rr) * H + o] = __float2bfloat16(acc[r] + bv);
    }
}

// ---------------- Kernel 2: gather2 (R4 shape, PLAIN stores) ------------------
__global__ __launch_bounds__(256) void gather2(
        const int* __restrict__ pos_s, const int* __restrict__ pos_e,
        const __hip_bfloat16* __restrict__ Y, float* __restrict__ out,
        int S, int ML, int NPE) {
    const int t  = threadIdx.x;
    const int w  = t >> 6;
    const int ln = t & 63;
    const int S8 = S >> 3;
    const int jbase = (blockIdx.x % S8) << 3;
    const int i     = (blockIdx.x / S8) % S;
    const int bb    = blockIdx.x / (S8 * S);
    const int j0    = jbase + (w << 1);
    const int j1    = j0 + 1;

    const int si = pos_s[bb * S + i];
    const int ei = pos_e[bb * S + i];
    const int sj0 = pos_s[bb * S + j0];
    const int ej0 = pos_e[bb * S + j0];
    const int sj1 = pos_s[bb * S + j1];
    const int ej1 = pos_e[bb * S + j1];

    const uint2* __restrict__ Yv = reinterpret_cast<const uint2*>(Y);
#define YIDX(r) (((size_t)(r) << 6) + ln)
    const int a0 = 0 * NPE + si - sj0 + ML, a1 = 1 * NPE + si - ej0 + ML;
    const int a2 = 2 * NPE + ei - sj0 + ML, a3 = 3 * NPE + ei - ej0 + ML;
    const int b0 = 0 * NPE + si - sj1 + ML, b1 = 1 * NPE + si - ej1 + ML;
    const int b2 = 2 * NPE + ei - sj1 + ML, b3 = 3 * NPE + ei - ej1 + ML;
    const uint2 uA0 = Yv[YIDX(a0)], uA1 = Yv[YIDX(a1)],
                uA2 = Yv[YIDX(a2)], uA3 = Yv[YIDX(a3)];
    const uint2 uB0 = Yv[YIDX(b0)], uB1 = Yv[YIDX(b1)],
                uB2 = Yv[YIDX(b2)], uB3 = Yv[YIDX(b3)];
#undef YIDX

    f32x4 vA, vB;
    vA.x = lrelu(bflo(uA0.x) + bflo(uA1.x) + bflo(uA2.x) + bflo(uA3.x));
    vA.y = lrelu(bfhi(uA0.x) + bfhi(uA1.x) + bfhi(uA2.x) + bfhi(uA3.x));
    vA.z = lrelu(bflo(uA0.y) + bflo(uA1.y) + bflo(uA2.y) + bflo(uA3.y));
    vA.w = lrelu(bfhi(uA0.y) + bfhi(uA1.y) + bfhi(uA2.y) + bfhi(uA3.y));
    vB.x = lrelu(bflo(uB0.x) + bflo(uB1.x) + bflo(uB2.x) + bflo(uB3.x));
    vB.y = lrelu(bfhi(uB0.x) + bfhi(uB1.x) + bfhi(uB2.x) + bfhi(uB3.x));
    vB.z = lrelu(bflo(uB0.y) + bflo(uB1.y) + bflo(uB2.y) + bflo(uB3.y));
    vB.w = lrelu(bfhi(uB0.y) + bfhi(uB1.y) + bfhi(uB2.y) + bfhi(uB3.y));

    const size_t orow = ((size_t)bb * S + i) * S;
    f32x4* __restrict__ ov = reinterpret_cast<f32x4*>(out);
    ov[((orow + j0) << 6) + ln] = vA;     // plain stores (A/B vs NT)
    ov[((orow + j1) << 6) + ln] = vB;
}

// ---------------- Fallback: direct compute ------------------------------------
__global__ void direct_kernel(const int* __restrict__ pos_s,
                              const int* __restrict__ pos_e,
                              const float* __restrict__ pe,
                              const float* __restrict__ W,
                              const float* __restrict__ bias,
                              float* __restrict__ out,
                              int B, int S, int H, int ML) {
    const int blk = blockIdx.x;
    const int j   = blk % S;
    const int i   = (blk / S) % S;
    const int bb  = blk / (S * S);
    const int o   = threadIdx.x;
    const int si = pos_s[bb * S + i];
    const int ei = pos_e[bb * S + i];
    const int sj = pos_s[bb * S + j];
    const int ej = pos_e[bb * S + j];
    const int rss = si - sj + ML, rse = si - ej + ML;
    const int res = ei - sj + ML, ree = ei - ej + ML;
    float acc = bias[o];
    for (int h = 0; h < H; ++h) {
        acc += pe[rss * H + h] * W[(0 * H + h) * H + o];
        acc += pe[rse * H + h] * W[(1 * H + h) * H + o];
        acc += pe[res * H + h] * W[(2 * H + h) * H + o];
        acc += pe[ree * H + h] * W[(3 * H + h) * H + o];
    }
    out[(((size_t)bb * S + i) * S + j) * H + o] = lrelu(acc);
}

extern "C" void kernel_launch(void* const* d_in, const int* in_sizes, int n_in,
                              void* d_out, int out_size, void* d_ws, size_t ws_size,
                              hipStream_t stream) {
    const int*   pos_s = (const int*)d_in[0];
    const int*   pos_e = (const int*)d_in[1];
    const float* pe    = (const float*)d_in[2];
    const float* W     = (const float*)d_in[3];
    const float* bias  = (const float*)d_in[4];
    float*       out   = (float*)d_out;

    const int H   = in_sizes[4];                 // 256
    const int NPE = in_sizes[2] / H;             // 1025
    const int ML  = (NPE - 1) / 2;               // 512
    const int BS  = in_sizes[0];
    const int S   = (int)((long long)out_size / ((long long)BS * H)); // 256
    const int B   = BS / S;

    const size_t ybytes = (size_t)4 * NPE * 256 * sizeof(__hip_bfloat16); // 2.1 MB

    if (H == 256 && (S & 7) == 0 && ws_size >= ybytes) {
        __hip_bfloat16* Y = (__hip_bfloat16*)d_ws;
        const int ntile = (NPE + 7) >> 3;
        precompute_Y<<<4 * ntile, 256, 0, stream>>>(pe, W, bias, Y, NPE);
        const int nblk = B * S * (S >> 3);
        gather2<<<nblk, 256, 0, stream>>>(pos_s, pos_e, Y, out, S, ML, NPE);
    } else {
        direct_kernel<<<B * S * S, H, 0, stream>>>(pos_s, pos_e, pe, W, bias, out,
                                                   B, S, H, ML);
    }
}